// Round 11
// baseline (119.887 us; speedup 1.0000x reference)
//
#include <hip/hip_runtime.h>
#include <math.h>

#define B 4
#define C 64
#define G 16
#define CPG 4
#define N 4096
#define TEMB 256

using f16x8 = __attribute__((ext_vector_type(8))) _Float16;
using f16x4 = __attribute__((ext_vector_type(4))) _Float16;
using f32x4 = __attribute__((ext_vector_type(4))) float;
using f32x16 = __attribute__((ext_vector_type(16))) float;
using h2 = __attribute__((ext_vector_type(2))) __fp16;

#define QSCALE 0.18033688f   // (1/8) * log2(e)
#define SHIFT2 4.328085f     // 3 * log2(e): exp-arg headroom shift (softmax-invariant)

// XOR swizzle on 16B granularity within a 64-f16 row.
__device__ __forceinline__ int swzi(int row, int ci) {
  return (((ci >> 3) ^ (row & 7)) << 3) | (ci & 7);
}

// GN finalize from 4 quarter-partials (layout [b][g][quarter])
__device__ __forceinline__ void gn_fin(const float2* pstats, const float* gamma,
                                       const float* beta, int b, int c,
                                       float& sc, float& sh) {
  int g = c >> 2;
  const float2* ps = pstats + ((size_t)(b * 16 + g)) * 4;
  float2 p0 = ps[0], p1 = ps[1], p2 = ps[2], p3 = ps[3];
  const float inv = 1.f / 16384.f;  // CPG*N
  float mean = (p0.x + p1.x + p2.x + p3.x) * inv;
  float msq = (p0.y + p1.y + p2.y + p3.y) * inv;
  float var = msq - mean * mean;
  float rstd = rsqrtf(var + 1e-5f);
  sc = gamma[c] * rstd;
  sh = beta[c] - mean * sc;
}

// GN finalize from reduced stats (layout [b*16+g], single float2)
__device__ __forceinline__ void gn_fin2(const float2* red, const float* gamma,
                                        const float* beta, int b, int c,
                                        float& sc, float& sh) {
  float2 r = red[b * 16 + (c >> 2)];
  const float inv = 1.f / 16384.f;
  float mean = r.x * inv;
  float var = r.y * inv - mean * mean;
  float rstd = rsqrtf(var + 1e-5f);
  sc = gamma[c] * rstd;
  sh = beta[c] - mean * sc;
}

// ---------------- GN partial stats for x: grid 256 = b(4) x g(16) x quarter(4)
__global__ void __launch_bounds__(256) k_gnpart(const float* __restrict__ x,
                                                float2* __restrict__ pstats) {
  int bx = blockIdx.x;
  const float4* xp = (const float4*)(x + (size_t)bx * 4096);
  float s = 0.f, s2 = 0.f;
#pragma unroll
  for (int kk = 0; kk < 4; kk++) {
    float4 v = xp[threadIdx.x + kk * 256];
    s += v.x + v.y + v.z + v.w;
    s2 += v.x * v.x + v.y * v.y + v.z * v.z + v.w * v.w;
  }
#pragma unroll
  for (int off = 32; off > 0; off >>= 1) {
    s += __shfl_down(s, off);
    s2 += __shfl_down(s2, off);
  }
  __shared__ float ls[4], ls2[4];
  int lane = threadIdx.x & 63, wid = threadIdx.x >> 6;
  if (lane == 0) { ls[wid] = s; ls2[wid] = s2; }
  __syncthreads();
  if (threadIdx.x == 0) {
    float2 r;
    r.x = ls[0] + ls[1] + ls[2] + ls[3];
    r.y = ls2[0] + ls2[1] + ls2[2] + ls2[3];
    pstats[bx] = r;
  }
}

// ---------------- reduce conv3 per-block stats [256][16] -> [b*16+g]
__global__ void k_gnred(const float2* __restrict__ blkstats, float2* __restrict__ red) {
  int tid = threadIdx.x;  // 256
  int pair = tid >> 2, q = tid & 3;
  int b = pair >> 4, g = pair & 15;
  float sx = 0.f, sy = 0.f;
  for (int i = 0; i < 16; i++) {
    float2 v = blkstats[(size_t)(b * 64 + q * 16 + i) * 16 + g];
    sx += v.x; sy += v.y;
  }
  sx += __shfl_xor(sx, 1); sy += __shfl_xor(sy, 1);
  sx += __shfl_xor(sx, 2); sy += __shfl_xor(sy, 2);
  if (q == 0) { float2 r; r.x = sx; r.y = sy; red[pair] = r; }
}

// ---------------- fused prep: wprep(conv1), wprep(conv2), tmlp
__global__ void __launch_bounds__(256) k_prep(const float* __restrict__ w1,
                                              const float* __restrict__ w2,
                                              const float* __restrict__ temb,
                                              const float* __restrict__ mlp_w,
                                              const float* __restrict__ mlp_b,
                                              _Float16* __restrict__ wf1,
                                              _Float16* __restrict__ wf2,
                                              float* __restrict__ tb) {
  int bx = blockIdx.x, tid = threadIdx.x;
  if (bx < 54) {
    const float* w = (bx < 27) ? w1 : w2;
    _Float16* wf = (bx < 27) ? wf1 : wf2;
    int tap = (bx < 27) ? bx : bx - 27;
    int co = tid >> 2, ci0 = (tid & 3) * 16;
    union { _Float16 hh[16]; f16x8 v[2]; } pk;
#pragma unroll
    for (int r = 0; r < 16; r++)
      pk.hh[r] = (_Float16)w[((size_t)(co * 64 + ci0 + r)) * 27 + tap];
    f16x8* dst = (f16x8*)(wf + ((size_t)tap * 64 + co) * 64 + ci0);
    dst[0] = pk.v[0]; dst[1] = pk.v[1];
  } else {
    int b = bx - 54;
    __shared__ float sw[TEMB];
    __shared__ float part[4][64];
    {
      float v = temb[b * TEMB + tid];
      sw[tid] = v / (1.f + __expf(-v));
    }
    __syncthreads();
    int co = tid & 63, seg = tid >> 6;
    float acc = 0.f;
#pragma unroll 16
    for (int k = 0; k < 64; k++) acc += sw[seg * 64 + k] * mlp_w[co * TEMB + seg * 64 + k];
    part[seg][co] = acc;
    __syncthreads();
    if (tid < 64) tb[b * C + tid] = part[0][tid] + part[1][tid] + part[2][tid] + part[3][tid] + mlp_b[tid];
  }
}

// ---------------- actT = swish(GN(in)) transposed to [b][n][c] f16
__global__ void __launch_bounds__(256) k_actT(const float* __restrict__ in,
                                              const float2* __restrict__ pstats,
                                              const float* __restrict__ gamma,
                                              const float* __restrict__ beta,
                                              _Float16* __restrict__ outT, int mode) {
  int b = blockIdx.x >> 6, nt = blockIdx.x & 63;
  int n0 = nt * 64;
  __shared__ float xl[64][68];
  int tid = threadIdx.x;
  {
    int c = tid >> 2, seg = tid & 3;
    float sc, sh;
    if (mode == 0) gn_fin(pstats, gamma, beta, b, c, sc, sh);
    else gn_fin2(pstats, gamma, beta, b, c, sc, sh);
    const float4* src = (const float4*)(in + ((size_t)(b * C + c)) * N + n0 + seg * 16);
#pragma unroll
    for (int j = 0; j < 4; j++) {
      float4 v = src[j];
      float t0 = v.x * sc + sh, t1 = v.y * sc + sh, t2 = v.z * sc + sh, t3 = v.w * sc + sh;
      xl[c][seg * 16 + j * 4 + 0] = t0 / (1.f + __expf(-t0));
      xl[c][seg * 16 + j * 4 + 1] = t1 / (1.f + __expf(-t1));
      xl[c][seg * 16 + j * 4 + 2] = t2 / (1.f + __expf(-t2));
      xl[c][seg * 16 + j * 4 + 3] = t3 / (1.f + __expf(-t3));
    }
  }
  __syncthreads();
  {
    int n = tid >> 2, cq = (tid & 3) * 16;
    union { _Float16 hh[16]; f16x8 v[2]; } pk;
#pragma unroll
    for (int r = 0; r < 16; r++) pk.hh[r] = (_Float16)xl[cq + r][n];
    f16x8* dst = (f16x8*)(outT + ((size_t)b * N + n0 + n) * 64 + cq);
    dst[0] = pk.v[0]; dst[1] = pk.v[1];
  }
}

// ---------------- fused MFMA 3x3x3 conv + bias/addvec/residual + GN partial stats
__global__ void __launch_bounds__(256) k_conv3(const _Float16* __restrict__ actT,
                                               const _Float16* __restrict__ wf,
                                               const float* __restrict__ bias,
                                               const float* __restrict__ addvec,
                                               const float* __restrict__ residual,
                                               float* __restrict__ out,
                                               float2* __restrict__ blkstats) {
  int bx = blockIdx.x;
  int b = bx >> 6, h = (bx >> 2) & 15, nog = bx & 3;
  int tid = threadIdx.x;
  int wv = tid >> 6, lane = tid & 63, hi = lane >> 5, l31 = lane & 31;
  int cw = wv >> 1, nw = wv & 1;
  __shared__ _Float16 a3[3][96][64];
  __shared__ _Float16 wl[2][64][64];
  __shared__ float2 sg[16];
  if (tid < 16) { sg[tid].x = 0.f; sg[tid].y = 0.f; }
  int w0 = nog * 4 - 1;
  for (int idx = tid; idx < 2304; idx += 256) {
    int r = idx / 768, rem = idx % 768;
    int ns = rem >> 3, ci8 = rem & 7;
    int wp = w0 + (ns >> 4), dp = ns & 15;
    int hin = h + r - 1;
    f16x8 v = {};
    if ((unsigned)hin < 16u && (unsigned)wp < 16u)
      v = *(const f16x8*)(actT + (((size_t)(b * 16 + hin)) * 256 + wp * 16 + dp) * 64 + ci8 * 8);
    *(f16x8*)&a3[r][ns][swzi(ns, ci8 * 8)] = v;
  }
#pragma unroll
  for (int q = 0; q < 2; q++) {
    int chunk = tid + q * 256;
    int co = chunk >> 3, ci8 = chunk & 7;
    f16x8 v = *(const f16x8*)(wf + (size_t)co * 64 + ci8 * 8);
    *(f16x8*)&wl[0][co][swzi(co, ci8 * 8)] = v;
  }
  f32x16 acc = {};
  __syncthreads();
  int cur = 0;
  int co_r = cw * 32 + l31;
  int n_loc = nw * 32 + l31;
  int wrow = n_loc >> 4;
  int d = n_loc & 15;
  for (int t = 0; t < 27; t++) {
    f16x8 pw0 = {}, pw1 = {};
    if (t < 26) {
      pw0 = *(const f16x8*)(wf + ((size_t)(t + 1) * 64 + (tid >> 3)) * 64 + (tid & 7) * 8);
      pw1 = *(const f16x8*)(wf + ((size_t)(t + 1) * 64 + ((tid + 256) >> 3)) * 64 + (tid & 7) * 8);
    }
    int kw = (t / 3) % 3, kd = t % 3, kh = t / 9;
    int wpl = wrow + kw;
    int dp = d + kd - 1;
    bool ok = (unsigned)dp < 16u;
    int ns = wpl * 16 + dp;
#pragma unroll
    for (int c4 = 0; c4 < 4; c4++) {
      int ci = c4 * 16 + hi * 8;
      f16x8 af = *(const f16x8*)&wl[cur][co_r][swzi(co_r, ci)];
      f16x8 bf = {};
      if (ok) bf = *(const f16x8*)&a3[kh][ns][swzi(ns, ci)];
      acc = __builtin_amdgcn_mfma_f32_32x32x16_f16(af, bf, acc, 0, 0, 0);
    }
    if (t < 26) {
      *(f16x8*)&wl[cur ^ 1][tid >> 3][swzi(tid >> 3, (tid & 7) * 8)] = pw0;
      *(f16x8*)&wl[cur ^ 1][(tid + 256) >> 3][swzi((tid + 256) >> 3, (tid & 7) * 8)] = pw1;
      __syncthreads();
      cur ^= 1;
    }
  }
  int nq = nog * 64 + n_loc;
  float gs[4] = {0.f, 0.f, 0.f, 0.f}, gs2[4] = {0.f, 0.f, 0.f, 0.f};
#pragma unroll
  for (int r = 0; r < 16; r++) {
    int co = cw * 32 + (r & 3) + 8 * (r >> 2) + 4 * hi;
    size_t off = (((size_t)(b * 64 + co)) * 16 + h) * 256 + nq;
    float vv = acc[r] + bias[co] + (addvec ? addvec[b * 64 + co] : 0.f);
    if (residual) vv += residual[off];
    out[off] = vv;
    gs[r >> 2] += vv;
    gs2[r >> 2] += vv * vv;
  }
#pragma unroll
  for (int off2 = 1; off2 < 32; off2 <<= 1)
#pragma unroll
    for (int rq = 0; rq < 4; rq++) {
      gs[rq] += __shfl_xor(gs[rq], off2);
      gs2[rq] += __shfl_xor(gs2[rq], off2);
    }
  if (l31 == 0) {
#pragma unroll
    for (int rq = 0; rq < 4; rq++) {
      int g = cw * 8 + 2 * rq + hi;
      atomicAdd(&sg[g].x, gs[rq]);
      atomicAdd(&sg[g].y, gs2[rq]);
    }
  }
  __syncthreads();
  if (tid < 16) blkstats[(size_t)bx * 16 + tid] = sg[tid];
}

// ---------------- qkv = qkv_w @ GN(x2); q scaled by QSCALE (reduced stats)
// outputs: q,k f16 [b][n][c]; v f16 tile-major [b][n/16][c][n%16]
__global__ void __launch_bounds__(256) k_qkv(const float* __restrict__ x2,
                                             const float2* __restrict__ red,
                                             const float* __restrict__ gamma,
                                             const float* __restrict__ beta,
                                             const float* __restrict__ w,
                                             _Float16* __restrict__ qh, _Float16* __restrict__ kh,
                                             _Float16* __restrict__ vh) {
  int b = blockIdx.x >> 6, nt = blockIdx.x & 63;
  int n0 = nt * 64;
  __shared__ __align__(16) float xl[64][64];
  __shared__ float wl[192 * 64];
  int tid = threadIdx.x;
  for (int i = tid; i < 192 * 64; i += 256) wl[i] = w[i];
  {
    int c = tid >> 2, seg = tid & 3;
    float sc, sh;
    gn_fin2(red, gamma, beta, b, c, sc, sh);
    const float4* src = (const float4*)(x2 + ((size_t)(b * C + c)) * N + n0);
    float4* dst = (float4*)&xl[c][seg * 16];
#pragma unroll
    for (int j = 0; j < 4; j++) {
      float4 v = src[seg * 4 + j];
      v.x = v.x * sc + sh; v.y = v.y * sc + sh; v.z = v.z * sc + sh; v.w = v.w * sc + sh;
      dst[j] = v;
    }
  }
  __syncthreads();
  int nq = tid & 15, og = tid >> 4;
  float4 acc[12];
#pragma unroll
  for (int j = 0; j < 12; j++) acc[j] = make_float4(0.f, 0.f, 0.f, 0.f);
  for (int c = 0; c < 64; c++) {
    float4 xv = *(const float4*)&xl[c][nq * 4];
#pragma unroll
    for (int j = 0; j < 12; j++) {
      float wv = wl[(og * 12 + j) * 64 + c];
      acc[j].x += wv * xv.x; acc[j].y += wv * xv.y; acc[j].z += wv * xv.z; acc[j].w += wv * xv.w;
    }
  }
#pragma unroll
  for (int j = 0; j < 12; j++) {
    int o3 = og * 12 + j;
    if (o3 >= 128) {
      f16x4 pv;
      pv[0] = (_Float16)acc[j].x; pv[1] = (_Float16)acc[j].y;
      pv[2] = (_Float16)acc[j].z; pv[3] = (_Float16)acc[j].w;
      int c = o3 - 128;
      int t = (n0 >> 4) + (nq >> 2);
      *(f16x4*)(vh + ((size_t)(b * 256 + t) * 64 + c) * 16 + (nq & 3) * 4) = pv;
    }
  }
  __syncthreads();
#pragma unroll
  for (int j = 0; j < 12; j++) {
    int o3 = og * 12 + j;
    if (o3 < 64) {
      float4 v = acc[j];
      v.x *= QSCALE; v.y *= QSCALE; v.z *= QSCALE; v.w *= QSCALE;
      *(float4*)&xl[o3][nq * 4] = v;
    }
  }
  __syncthreads();
  {
    int n_ = tid >> 2, cs = (tid & 3) * 16;
    union { _Float16 hh[16]; uint4 u[2]; } pk;
#pragma unroll
    for (int r = 0; r < 16; r++) pk.hh[r] = (_Float16)xl[cs + r][n_];
    uint4* dst = (uint4*)(qh + ((size_t)b * N + n0 + n_) * 64 + cs);
    dst[0] = pk.u[0]; dst[1] = pk.u[1];
  }
  __syncthreads();
#pragma unroll
  for (int j = 0; j < 12; j++) {
    int o3 = og * 12 + j;
    if (o3 >= 64 && o3 < 128) *(float4*)&xl[o3 - 64][nq * 4] = acc[j];
  }
  __syncthreads();
  {
    int n_ = tid >> 2, cs = (tid & 3) * 16;
    union { _Float16 hh[16]; uint4 u[2]; } pk;
#pragma unroll
    for (int r = 0; r < 16; r++) pk.hh[r] = (_Float16)xl[cs + r][n_];
    uint4* dst = (uint4*)(kh + ((size_t)b * N + n0 + n_) * 64 + cs);
    dst[0] = pk.u[0]; dst[1] = pk.u[1];
  }
}

// ---------------- barrier-free MFMA flash attention, 4-way split, 64q/block
// grid 1024 = s(4) x b(4) x qtile(64). Wave wv owns key tiles (it*4+wv)*16 in its
// 1024-key split. Unroll-2 + depth-2 prefetch (named register generations) so
// loads issued at pair p are consumed at pair p+1 (~2 iters of latency cover).
// Denominator on the VALU pipe (frees the MFMA pipe + 12 registers vs ones-MFMA).
__global__ void __launch_bounds__(256) k_attn(const _Float16* __restrict__ q,
                                              const _Float16* __restrict__ k,
                                              const _Float16* __restrict__ v,
                                              _Float16* __restrict__ po,
                                              float* __restrict__ pl) {
  int bx = blockIdx.x;
  int s = bx >> 8, b = (bx >> 6) & 3, nt = bx & 63;
  int n0 = nt * 64;
  int tid = threadIdx.x;
  int wv = tid >> 6, lane = tid & 63, lg = lane >> 4, ll = lane & 15;
  __shared__ float ol[64][72];    // O^T accum, [query][channel]
  __shared__ float lsum[4][64];
  const _Float16* qp = q + (size_t)b * N * 64;
  f16x8 qf[4][2];
#pragma unroll
  for (int qb = 0; qb < 4; qb++)
#pragma unroll
    for (int ch = 0; ch < 2; ch++)
      qf[qb][ch] = *(const f16x8*)(qp + (size_t)(n0 + qb * 16 + ll) * 64 + ch * 32 + lg * 8);
  f32x4 oacc[4][4] = {};  // [qb][cb]
  float lacc[4] = {0.f, 0.f, 0.f, 0.f};
  const _Float16* kptr = k + (size_t)b * N * 64 + (size_t)(s * 1024 + wv * 16 + ll) * 64 + lg * 8;
  const _Float16* vptr = v + ((size_t)(b * 256 + s * 64 + wv) * 64 + ll) * 16 + lg * 4;

  auto iter = [&](f16x8 kf0, f16x8 kf1, const f16x4 (&vf)[4]) {
    f32x4 sv[4];
    __builtin_amdgcn_s_setprio(1);
#pragma unroll
    for (int qb = 0; qb < 4; qb++) {
      f32x4 z = {-SHIFT2, -SHIFT2, -SHIFT2, -SHIFT2};
      z = __builtin_amdgcn_mfma_f32_16x16x32_f16(kf0, qf[qb][0], z, 0, 0, 0);
      sv[qb] = __builtin_amdgcn_mfma_f32_16x16x32_f16(kf1, qf[qb][1], z, 0, 0, 0);
    }
    __builtin_amdgcn_s_setprio(0);
    f16x4 pk[4];
#pragma unroll
    for (int qb = 0; qb < 4; qb++) {
      float e0 = __builtin_amdgcn_exp2f(sv[qb][0]);
      float e1 = __builtin_amdgcn_exp2f(sv[qb][1]);
      float e2 = __builtin_amdgcn_exp2f(sv[qb][2]);
      float e3 = __builtin_amdgcn_exp2f(sv[qb][3]);
      lacc[qb] += (e0 + e1) + (e2 + e3);
      union { h2 h[2]; f16x4 v4; } u;
      u.h[0] = __builtin_amdgcn_cvt_pkrtz(e0, e1);
      u.h[1] = __builtin_amdgcn_cvt_pkrtz(e2, e3);
      pk[qb] = u.v4;
    }
    __builtin_amdgcn_s_setprio(1);
#pragma unroll
    for (int qb = 0; qb < 4; qb++)
#pragma unroll
      for (int cb = 0; cb < 4; cb++)
        oacc[qb][cb] = __builtin_amdgcn_mfma_f32_16x16x16f16(vf[cb], pk[qb], oacc[qb][cb], 0, 0, 0);
    __builtin_amdgcn_s_setprio(0);
  };

  // generation A = even iters, generation B = odd iters
  f16x8 ka0 = *(const f16x8*)(kptr);
  f16x8 ka1 = *(const f16x8*)(kptr + 32);
  f16x8 kb0 = *(const f16x8*)(kptr + 4096);
  f16x8 kb1 = *(const f16x8*)(kptr + 4096 + 32);
  f16x4 va[4], vb[4];
#pragma unroll
  for (int cb = 0; cb < 4; cb++) {
    va[cb] = *(const f16x4*)(vptr + cb * 256);
    vb[cb] = *(const f16x4*)(vptr + 4096 + cb * 256);
  }
  for (int ip = 0; ip < 8; ip++) {
    const _Float16* kp2 = kptr + 8192;
    const _Float16* vp2 = vptr + 8192;
    // prefetch even gen of next pair (consumed ~2 iters later; tail overreads
    // stay inside adjacent allocated ws buffers - read-only, safe)
    f16x8 na0 = *(const f16x8*)(kp2);
    f16x8 na1 = *(const f16x8*)(kp2 + 32);
    f16x4 nva[4];
#pragma unroll
    for (int cb = 0; cb < 4; cb++) nva[cb] = *(const f16x4*)(vp2 + cb * 256);
    iter(ka0, ka1, va);
    ka0 = na0; ka1 = na1;
#pragma unroll
    for (int cb = 0; cb < 4; cb++) va[cb] = nva[cb];
    // prefetch odd gen of next pair
    f16x8 nb0 = *(const f16x8*)(kp2 + 4096);
    f16x8 nb1 = *(const f16x8*)(kp2 + 4096 + 32);
    f16x4 nvb[4];
#pragma unroll
    for (int cb = 0; cb < 4; cb++) nvb[cb] = *(const f16x4*)(vp2 + 4096 + cb * 256);
    iter(kb0, kb1, vb);
    kb0 = nb0; kb1 = nb1;
#pragma unroll
    for (int cb = 0; cb < 4; cb++) vb[cb] = nvb[cb];
    kptr = kp2; vptr = vp2;
  }
  // denominator: sum over lane groups (keys 4lg+reg) then over waves
#pragma unroll
  for (int qb = 0; qb < 4; qb++) {
    lacc[qb] += __shfl_xor(lacc[qb], 16);
    lacc[qb] += __shfl_xor(lacc[qb], 32);
  }
  if (lane < 16) {
#pragma unroll
    for (int qb = 0; qb < 4; qb++) lsum[wv][qb * 16 + lane] = lacc[qb];
  }
  // cross-wave O reduce: sequential accumulate rounds
  for (int w = 0; w < 4; w++) {
    __syncthreads();
    if (wv == w) {
#pragma unroll
      for (int qb = 0; qb < 4; qb++)
#pragma unroll
        for (int cb = 0; cb < 4; cb++) {
          float* a = &ol[qb * 16 + ll][cb * 16 + 4 * lg];
          if (w == 0) {
            *(f32x4*)a = oacc[qb][cb];
          } else {
            f32x4 t = *(f32x4*)a;
            t += oacc[qb][cb];
            *(f32x4*)a = t;
          }
        }
    }
  }
  __syncthreads();
  {
    int n = tid >> 2, cq = (tid & 3) * 16;
    float lt = lsum[0][n] + lsum[1][n] + lsum[2][n] + lsum[3][n];
    float inv = 1.f / lt;
    union { _Float16 hh[16]; uint4 u[2]; } pk2;
#pragma unroll
    for (int j = 0; j < 16; j++) pk2.hh[j] = (_Float16)(ol[n][cq + j] * inv);
    uint4* dst = (uint4*)(po + ((size_t)(s * 4 + b) * N + n0 + n) * 64 + cq);
    dst[0] = pk2.u[0]; dst[1] = pk2.u[1];
    if (tid < 64)
      pl[(size_t)(s * 4 + b) * N + n0 + tid] =
          lsum[0][tid] + lsum[1][tid] + lsum[2][tid] + lsum[3][tid];
  }
}

// ---------- out = out_w @ (4-split combine of po) + out_b + x2   (writes d_out)
__global__ void __launch_bounds__(256) k_outproj(const _Float16* __restrict__ po,
                                                 const float* __restrict__ pl,
                                                 const float* __restrict__ w,
                                                 const float* __restrict__ bias,
                                                 const float* __restrict__ x2,
                                                 float* __restrict__ out) {
  int b = blockIdx.x >> 6, nt = blockIdx.x & 63;
  int n0 = nt * 64;
  __shared__ __align__(16) float wl2[64][68];
  __shared__ __align__(16) float ol[64][68];
  __shared__ float wsc[4][64];
  int tid = threadIdx.x;
  if (tid < 64) {
    float l0 = pl[((size_t)(0 * 4 + b)) * N + n0 + tid];
    float l1 = pl[((size_t)(1 * 4 + b)) * N + n0 + tid];
    float l2 = pl[((size_t)(2 * 4 + b)) * N + n0 + tid];
    float l3 = pl[((size_t)(3 * 4 + b)) * N + n0 + tid];
    float inv = 1.f / (l0 + l1 + l2 + l3);
    wsc[0][tid] = l0 * inv; wsc[1][tid] = l1 * inv;
    wsc[2][tid] = l2 * inv; wsc[3][tid] = l3 * inv;
  }
  for (int i = tid; i < 4096; i += 256) wl2[i >> 6][i & 63] = w[i];
  __syncthreads();
  for (int base = tid; base < 1024; base += 256) {
    int n = base >> 4, c0 = (base & 15) * 4;
    float a0 = 0.f, a1 = 0.f, a2 = 0.f, a3 = 0.f;
#pragma unroll
    for (int s = 0; s < 4; s++) {
      f16x4 pv = *(const f16x4*)&po[((size_t)(s * 4 + b) * N + n0 + n) * 64 + c0];
      float wsv = wsc[s][n];
      a0 += (float)pv[0] * wsv; a1 += (float)pv[1] * wsv;
      a2 += (float)pv[2] * wsv; a3 += (float)pv[3] * wsv;
    }
    ol[n][c0] = a0; ol[n][c0 + 1] = a1; ol[n][c0 + 2] = a2; ol[n][c0 + 3] = a3;
  }
  __syncthreads();
  int co = tid & 63, ng = tid >> 6;
  float acc16[16];
#pragma unroll
  for (int i = 0; i < 16; i++) acc16[i] = 0.f;
  for (int c4 = 0; c4 < 16; c4++) {
    float4 wv = *(const float4*)&wl2[co][c4 * 4];
#pragma unroll
    for (int i = 0; i < 16; i++) {
      float4 ov = *(const float4*)&ol[ng * 16 + i][c4 * 4];
      acc16[i] += wv.x * ov.x + wv.y * ov.y + wv.z * ov.z + wv.w * ov.w;
    }
  }
  float bv = bias[co];
  __syncthreads();
#pragma unroll
  for (int i = 0; i < 16; i++) ol[ng * 16 + i][co] = acc16[i] + bv;
  __syncthreads();
  for (int kk = 0; kk < 16; kk++) {
    int i = tid + kk * 256;
    int c2 = i >> 6, nl = i & 63;
    size_t idx = ((size_t)(b * C + c2)) * N + n0 + nl;
    out[idx] = ol[nl][c2] + x2[idx];
  }
}

extern "C" void kernel_launch(void* const* d_in, const int* in_sizes, int n_in,
                              void* d_out, int out_size, void* d_ws, size_t ws_size,
                              hipStream_t stream) {
  (void)in_sizes; (void)n_in; (void)out_size; (void)ws_size;
  const float* x       = (const float*)d_in[0];
  const float* temb    = (const float*)d_in[1];
  const float* gn1_g   = (const float*)d_in[2];
  const float* gn1_b   = (const float*)d_in[3];
  const float* conv1_w = (const float*)d_in[4];
  const float* conv1_b = (const float*)d_in[5];
  const float* mlp_w   = (const float*)d_in[6];
  const float* mlp_b   = (const float*)d_in[7];
  const float* gn2_g   = (const float*)d_in[8];
  const float* gn2_b   = (const float*)d_in[9];
  const float* conv2_w = (const float*)d_in[10];
  const float* conv2_b = (const float*)d_in[11];
  const float* agn_g   = (const float*)d_in[12];
  const float* agn_b   = (const float*)d_in[13];
  const float* qkv_w   = (const float*)d_in[14];
  const float* out_w   = (const float*)d_in[15];
  const float* out_b   = (const float*)d_in[16];
  float* out = (float*)d_out;
  float* ws = (float*)d_ws;
  const size_t F = 1048576;
  float* h        = ws;                         // conv1 out, later x2
  _Float16* qh    = (_Float16*)(ws + F);        // f16 [b][n][c]
  _Float16* khb   = qh + F;                     // f16 [b][n][c]
  _Float16* vhb   = khb + F;                    // f16 tile-major [b][n/16][c][n%16]
  float2* pst1 = (float2*)(vhb + F);            // 256 float2 (x stats, quarters)
  float* tb    = (float*)(pst1 + 256);          // 256
  _Float16* wf1 = (_Float16*)(tb + 256);        // 110592 f16
  _Float16* wf2 = wf1 + 27 * 64 * 64;
  _Float16* actT = wf2 + 27 * 64 * 64;          // 1M f16; dead after conv2
  _Float16* po   = actT;                        // 4M f16 overlay (written post-conv)
  float* pl      = (float*)(po + 4 * F);        // 65536 floats
  float2* pstb1  = (float2*)(pl + 65536);       // 4096 float2 (conv1 block stats)
  float2* pstb2  = pstb1 + 4096;                // 4096 float2 (conv2 block stats)
  float2* red2   = pstb2 + 4096;                // 64 float2
  float2* red3   = red2 + 64;                   // 64 float2

  k_prep<<<58, 256, 0, stream>>>(conv1_w, conv2_w, temb, mlp_w, mlp_b, wf1, wf2, tb);
  k_gnpart<<<256, 256, 0, stream>>>(x, pst1);
  k_actT<<<256, 256, 0, stream>>>(x, pst1, gn1_g, gn1_b, actT, 0);
  k_conv3<<<256, 256, 0, stream>>>(actT, wf1, conv1_b, tb, nullptr, h, pstb1);
  k_gnred<<<1, 256, 0, stream>>>(pstb1, red2);
  k_actT<<<256, 256, 0, stream>>>(h, (const float2*)red2, gn2_g, gn2_b, actT, 1);
  k_conv3<<<256, 256, 0, stream>>>(actT, wf2, conv2_b, nullptr, x, h, pstb2);  // h = x2
  k_gnred<<<1, 256, 0, stream>>>(pstb2, red3);
  k_qkv<<<256, 256, 0, stream>>>(h, (const float2*)red3, agn_g, agn_b, qkv_w, qh, khb, vhb);
  k_attn<<<1024, 256, 0, stream>>>(qh, khb, vhb, po, pl);
  k_outproj<<<256, 256, 0, stream>>>(po, pl, out_w, out_b, h, out);
}

// Round 12
// 114.477 us; speedup vs baseline: 1.0473x; 1.0473x over previous
//
#include <hip/hip_runtime.h>
#include <math.h>

#define B 4
#define C 64
#define G 16
#define CPG 4
#define N 4096
#define TEMB 256

using f16x8 = __attribute__((ext_vector_type(8))) _Float16;
using f16x4 = __attribute__((ext_vector_type(4))) _Float16;
using f32x4 = __attribute__((ext_vector_type(4))) float;
using f32x16 = __attribute__((ext_vector_type(16))) float;
using h2 = __attribute__((ext_vector_type(2))) __fp16;

#define QSCALE 0.18033688f   // (1/8) * log2(e)
#define SHIFT2 4.328085f     // 3 * log2(e): exp-arg headroom shift (softmax-invariant)

// XOR swizzle on 16B granularity within a 64-f16 row.
__device__ __forceinline__ int swzi(int row, int ci) {
  return (((ci >> 3) ^ (row & 7)) << 3) | (ci & 7);
}

// GN finalize from 4 quarter-partials (layout [b][g][quarter])
__device__ __forceinline__ void gn_fin(const float2* pstats, const float* gamma,
                                       const float* beta, int b, int c,
                                       float& sc, float& sh) {
  int g = c >> 2;
  const float2* ps = pstats + ((size_t)(b * 16 + g)) * 4;
  float2 p0 = ps[0], p1 = ps[1], p2 = ps[2], p3 = ps[3];
  const float inv = 1.f / 16384.f;  // CPG*N
  float mean = (p0.x + p1.x + p2.x + p3.x) * inv;
  float msq = (p0.y + p1.y + p2.y + p3.y) * inv;
  float var = msq - mean * mean;
  float rstd = rsqrtf(var + 1e-5f);
  sc = gamma[c] * rstd;
  sh = beta[c] - mean * sc;
}

// ---------------- GN partial stats: grid 256 = b(4) x g(16) x quarter(4)
__global__ void __launch_bounds__(256) k_gnpart(const float* __restrict__ x,
                                                float2* __restrict__ pstats) {
  int bx = blockIdx.x;
  const float4* xp = (const float4*)(x + (size_t)bx * 4096);
  float s = 0.f, s2 = 0.f;
#pragma unroll
  for (int kk = 0; kk < 4; kk++) {
    float4 v = xp[threadIdx.x + kk * 256];
    s += v.x + v.y + v.z + v.w;
    s2 += v.x * v.x + v.y * v.y + v.z * v.z + v.w * v.w;
  }
#pragma unroll
  for (int off = 32; off > 0; off >>= 1) {
    s += __shfl_down(s, off);
    s2 += __shfl_down(s2, off);
  }
  __shared__ float ls[4], ls2[4];
  int lane = threadIdx.x & 63, wid = threadIdx.x >> 6;
  if (lane == 0) { ls[wid] = s; ls2[wid] = s2; }
  __syncthreads();
  if (threadIdx.x == 0) {
    float2 r;
    r.x = ls[0] + ls[1] + ls[2] + ls[3];
    r.y = ls2[0] + ls2[1] + ls2[2] + ls2[3];
    pstats[bx] = r;
  }
}

// ---------------- merged prep: wprep(conv1), wprep(conv2), tmlp, gnpart(x)
// grid 314: 0-26 wf1, 27-53 wf2, 54-57 tmlp(b), 58-313 gnpart(x)
__global__ void __launch_bounds__(256) k_prepgn(const float* __restrict__ w1,
                                                const float* __restrict__ w2,
                                                const float* __restrict__ temb,
                                                const float* __restrict__ mlp_w,
                                                const float* __restrict__ mlp_b,
                                                const float* __restrict__ x,
                                                _Float16* __restrict__ wf1,
                                                _Float16* __restrict__ wf2,
                                                float* __restrict__ tb,
                                                float2* __restrict__ pstats) {
  int bx = blockIdx.x, tid = threadIdx.x;
  __shared__ float sw[TEMB];
  __shared__ float part[4][64];
  __shared__ float ls[4], ls2[4];
  if (bx < 54) {
    const float* w = (bx < 27) ? w1 : w2;
    _Float16* wf = (bx < 27) ? wf1 : wf2;
    int tap = (bx < 27) ? bx : bx - 27;
    int co = tid >> 2, ci0 = (tid & 3) * 16;
    union { _Float16 hh[16]; f16x8 v[2]; } pk;
#pragma unroll
    for (int r = 0; r < 16; r++)
      pk.hh[r] = (_Float16)w[((size_t)(co * 64 + ci0 + r)) * 27 + tap];
    f16x8* dst = (f16x8*)(wf + ((size_t)tap * 64 + co) * 64 + ci0);
    dst[0] = pk.v[0]; dst[1] = pk.v[1];
  } else if (bx < 58) {
    int b = bx - 54;
    {
      float v = temb[b * TEMB + tid];
      sw[tid] = v / (1.f + __expf(-v));
    }
    __syncthreads();
    int co = tid & 63, seg = tid >> 6;
    float acc = 0.f;
#pragma unroll 16
    for (int k = 0; k < 64; k++) acc += sw[seg * 64 + k] * mlp_w[co * TEMB + seg * 64 + k];
    part[seg][co] = acc;
    __syncthreads();
    if (tid < 64) tb[b * C + tid] = part[0][tid] + part[1][tid] + part[2][tid] + part[3][tid] + mlp_b[tid];
  } else {
    int bx2 = bx - 58;
    const float4* xp = (const float4*)(x + (size_t)bx2 * 4096);
    float s = 0.f, s2 = 0.f;
#pragma unroll
    for (int kk = 0; kk < 4; kk++) {
      float4 v = xp[tid + kk * 256];
      s += v.x + v.y + v.z + v.w;
      s2 += v.x * v.x + v.y * v.y + v.z * v.z + v.w * v.w;
    }
#pragma unroll
    for (int off = 32; off > 0; off >>= 1) {
      s += __shfl_down(s, off);
      s2 += __shfl_down(s2, off);
    }
    int lane = tid & 63, wid = tid >> 6;
    if (lane == 0) { ls[wid] = s; ls2[wid] = s2; }
    __syncthreads();
    if (tid == 0) {
      float2 r;
      r.x = ls[0] + ls[1] + ls[2] + ls[3];
      r.y = ls2[0] + ls2[1] + ls2[2] + ls2[3];
      pstats[bx2] = r;
    }
  }
}

// ---------------- fused MFMA 3x3x3 conv with inline GN+swish on the INPUT
// in: raw fp32 [b][ci][h][w][d]; staging applies swish(in*sc+sh) and packs f16.
// grid 256 = b(4) x h(16) x nog(4); block 256 = 4 waves, each one 32co x 32n tile
__global__ void __launch_bounds__(256) k_conv3f(const float* __restrict__ in,
                                                const float2* __restrict__ pstats,
                                                const float* __restrict__ gamma,
                                                const float* __restrict__ beta,
                                                const _Float16* __restrict__ wf,
                                                const float* __restrict__ bias,
                                                const float* __restrict__ addvec,
                                                const float* __restrict__ residual,
                                                float* __restrict__ out) {
  int bx = blockIdx.x;
  int b = bx >> 6, h = (bx >> 2) & 15, nog = bx & 3;
  int tid = threadIdx.x;
  int wv = tid >> 6, lane = tid & 63, hi = lane >> 5, l31 = lane & 31;
  int cw = wv >> 1, nw = wv & 1;
  __shared__ _Float16 a3[3][96][64];
  __shared__ _Float16 wl[2][64][64];
  __shared__ float2 scsh[64];
  if (tid < 64) {
    float sc, sh;
    gn_fin(pstats, gamma, beta, b, tid, sc, sh);
    float2 r; r.x = sc; r.y = sh;
    scsh[tid] = r;
  }
  __syncthreads();  // scsh ready
  int w0 = nog * 4 - 1;
  // stage: unit = (r, ci8, ns); ns-fastest over lanes -> coalesced 256B per load instr
  for (int i = tid; i < 2304; i += 256) {
    int r = i / 768, rem = i % 768;
    int ci8 = rem / 96, ns = rem % 96;
    int wp = w0 + (ns >> 4), dd = ns & 15;
    int hin = h + r - 1;
    f16x8 val = {};
    if ((unsigned)hin < 16u && (unsigned)wp < 16u) {
      const float* src = in + (((size_t)(b * 64 + ci8 * 8) * 16 + hin) * 256) + wp * 16 + dd;
      union { _Float16 hh[8]; f16x8 v; } pk;
#pragma unroll
      for (int j = 0; j < 8; j++) {
        float v = src[(size_t)j * 4096];
        float2 ss = scsh[ci8 * 8 + j];
        float t = v * ss.x + ss.y;
        pk.hh[j] = (_Float16)(t / (1.f + __expf(-t)));
      }
      val = pk.v;
    }
    *(f16x8*)&a3[r][ns][swzi(ns, ci8 * 8)] = val;
  }
#pragma unroll
  for (int q = 0; q < 2; q++) {
    int chunk = tid + q * 256;
    int co = chunk >> 3, ci8 = chunk & 7;
    f16x8 v = *(const f16x8*)(wf + (size_t)co * 64 + ci8 * 8);
    *(f16x8*)&wl[0][co][swzi(co, ci8 * 8)] = v;
  }
  f32x16 acc = {};
  __syncthreads();
  int cur = 0;
  int co_r = cw * 32 + l31;
  int n_loc = nw * 32 + l31;
  int wrow = n_loc >> 4;
  int d = n_loc & 15;
  for (int t = 0; t < 27; t++) {
    f16x8 pw0 = {}, pw1 = {};
    if (t < 26) {
      pw0 = *(const f16x8*)(wf + ((size_t)(t + 1) * 64 + (tid >> 3)) * 64 + (tid & 7) * 8);
      pw1 = *(const f16x8*)(wf + ((size_t)(t + 1) * 64 + ((tid + 256) >> 3)) * 64 + (tid & 7) * 8);
    }
    int kw = (t / 3) % 3, kd = t % 3, kh = t / 9;
    int wpl = wrow + kw;
    int dp = d + kd - 1;
    bool ok = (unsigned)dp < 16u;
    int ns = wpl * 16 + dp;
#pragma unroll
    for (int c4 = 0; c4 < 4; c4++) {
      int ci = c4 * 16 + hi * 8;
      f16x8 af = *(const f16x8*)&wl[cur][co_r][swzi(co_r, ci)];
      f16x8 bf = {};
      if (ok) bf = *(const f16x8*)&a3[kh][ns][swzi(ns, ci)];
      acc = __builtin_amdgcn_mfma_f32_32x32x16_f16(af, bf, acc, 0, 0, 0);
    }
    if (t < 26) {
      *(f16x8*)&wl[cur ^ 1][tid >> 3][swzi(tid >> 3, (tid & 7) * 8)] = pw0;
      *(f16x8*)&wl[cur ^ 1][(tid + 256) >> 3][swzi((tid + 256) >> 3, (tid & 7) * 8)] = pw1;
      __syncthreads();
      cur ^= 1;
    }
  }
  int nq = nog * 64 + n_loc;
#pragma unroll
  for (int r = 0; r < 16; r++) {
    int co = cw * 32 + (r & 3) + 8 * (r >> 2) + 4 * hi;
    size_t off = (((size_t)(b * 64 + co)) * 16 + h) * 256 + nq;
    float vv = acc[r] + bias[co] + (addvec ? addvec[b * 64 + co] : 0.f);
    if (residual) vv += residual[off];
    out[off] = vv;
  }
}

// ---------------- qkv = qkv_w @ GN(x2); q scaled by QSCALE (quarter stats)
// outputs: q,k f16 [b][n][c]; v f16 tile-major [b][n/16][c][n%16]
__global__ void __launch_bounds__(256) k_qkv(const float* __restrict__ x2,
                                             const float2* __restrict__ pstats,
                                             const float* __restrict__ gamma,
                                             const float* __restrict__ beta,
                                             const float* __restrict__ w,
                                             _Float16* __restrict__ qh, _Float16* __restrict__ kh,
                                             _Float16* __restrict__ vh) {
  int b = blockIdx.x >> 6, nt = blockIdx.x & 63;
  int n0 = nt * 64;
  __shared__ __align__(16) float xl[64][64];
  __shared__ float wl[192 * 64];
  int tid = threadIdx.x;
  for (int i = tid; i < 192 * 64; i += 256) wl[i] = w[i];
  {
    int c = tid >> 2, seg = tid & 3;
    float sc, sh;
    gn_fin(pstats, gamma, beta, b, c, sc, sh);
    const float4* src = (const float4*)(x2 + ((size_t)(b * C + c)) * N + n0);
    float4* dst = (float4*)&xl[c][seg * 16];
#pragma unroll
    for (int j = 0; j < 4; j++) {
      float4 v = src[seg * 4 + j];
      v.x = v.x * sc + sh; v.y = v.y * sc + sh; v.z = v.z * sc + sh; v.w = v.w * sc + sh;
      dst[j] = v;
    }
  }
  __syncthreads();
  int nq = tid & 15, og = tid >> 4;
  float4 acc[12];
#pragma unroll
  for (int j = 0; j < 12; j++) acc[j] = make_float4(0.f, 0.f, 0.f, 0.f);
  for (int c = 0; c < 64; c++) {
    float4 xv = *(const float4*)&xl[c][nq * 4];
#pragma unroll
    for (int j = 0; j < 12; j++) {
      float wv = wl[(og * 12 + j) * 64 + c];
      acc[j].x += wv * xv.x; acc[j].y += wv * xv.y; acc[j].z += wv * xv.z; acc[j].w += wv * xv.w;
    }
  }
#pragma unroll
  for (int j = 0; j < 12; j++) {
    int o3 = og * 12 + j;
    if (o3 >= 128) {
      f16x4 pv;
      pv[0] = (_Float16)acc[j].x; pv[1] = (_Float16)acc[j].y;
      pv[2] = (_Float16)acc[j].z; pv[3] = (_Float16)acc[j].w;
      int c = o3 - 128;
      int t = (n0 >> 4) + (nq >> 2);
      *(f16x4*)(vh + ((size_t)(b * 256 + t) * 64 + c) * 16 + (nq & 3) * 4) = pv;
    }
  }
  __syncthreads();
#pragma unroll
  for (int j = 0; j < 12; j++) {
    int o3 = og * 12 + j;
    if (o3 < 64) {
      float4 v = acc[j];
      v.x *= QSCALE; v.y *= QSCALE; v.z *= QSCALE; v.w *= QSCALE;
      *(float4*)&xl[o3][nq * 4] = v;
    }
  }
  __syncthreads();
  {
    int n_ = tid >> 2, cs = (tid & 3) * 16;
    union { _Float16 hh[16]; uint4 u[2]; } pk;
#pragma unroll
    for (int r = 0; r < 16; r++) pk.hh[r] = (_Float16)xl[cs + r][n_];
    uint4* dst = (uint4*)(qh + ((size_t)b * N + n0 + n_) * 64 + cs);
    dst[0] = pk.u[0]; dst[1] = pk.u[1];
  }
  __syncthreads();
#pragma unroll
  for (int j = 0; j < 12; j++) {
    int o3 = og * 12 + j;
    if (o3 >= 64 && o3 < 128) *(float4*)&xl[o3 - 64][nq * 4] = acc[j];
  }
  __syncthreads();
  {
    int n_ = tid >> 2, cs = (tid & 3) * 16;
    union { _Float16 hh[16]; uint4 u[2]; } pk;
#pragma unroll
    for (int r = 0; r < 16; r++) pk.hh[r] = (_Float16)xl[cs + r][n_];
    uint4* dst = (uint4*)(kh + ((size_t)b * N + n0 + n_) * 64 + cs);
    dst[0] = pk.u[0]; dst[1] = pk.u[1];
  }
}

// ---------------- barrier-free MFMA flash attention (r7 config: best measured)
// grid 1024 = s(4) x b(4) x qtile(64); 4 waves; induction addressing; ones-MFMA denom
__global__ void __launch_bounds__(256) k_attn(const _Float16* __restrict__ q,
                                              const _Float16* __restrict__ k,
                                              const _Float16* __restrict__ v,
                                              _Float16* __restrict__ po,
                                              float* __restrict__ pl) {
  int bx = blockIdx.x;
  int s = bx >> 8, b = (bx >> 6) & 3, nt = bx & 63;
  int n0 = nt * 64;
  int tid = threadIdx.x;
  int wv = tid >> 6, lane = tid & 63, lg = lane >> 4, ll = lane & 15;
  __shared__ float ol[64][72];    // O^T accum, [query][channel]
  __shared__ float lsum[4][64];
  const _Float16* qp = q + (size_t)b * N * 64;
  f16x8 qf[4][2];
#pragma unroll
  for (int qb = 0; qb < 4; qb++)
#pragma unroll
    for (int ch = 0; ch < 2; ch++)
      qf[qb][ch] = *(const f16x8*)(qp + (size_t)(n0 + qb * 16 + ll) * 64 + ch * 32 + lg * 8);
  f32x4 oacc[4][4] = {};  // [qb][cb]
  f32x4 lfrag[4] = {};    // denominator fragments (all regs identical per lane)
  const f16x4 ones = {(_Float16)1.f, (_Float16)1.f, (_Float16)1.f, (_Float16)1.f};
  const _Float16* kptr = k + (size_t)b * N * 64 + (size_t)(s * 1024 + wv * 16 + ll) * 64 + lg * 8;
  const _Float16* vptr = v + ((size_t)(b * 256 + s * 64 + wv) * 64 + ll) * 16 + lg * 4;
  f16x8 kf0 = *(const f16x8*)(kptr);
  f16x8 kf1 = *(const f16x8*)(kptr + 32);
  f16x4 vf[4];
#pragma unroll
  for (int cb = 0; cb < 4; cb++) vf[cb] = *(const f16x4*)(vptr + cb * 256);
  for (int it = 0; it < 16; it++) {
    const _Float16* kptrn = kptr + 4096;
    const _Float16* vptrn = vptr + 4096;
    f32x4 sv[4];
    __builtin_amdgcn_s_setprio(1);
#pragma unroll
    for (int qb = 0; qb < 4; qb++) {
      f32x4 z = {-SHIFT2, -SHIFT2, -SHIFT2, -SHIFT2};
      z = __builtin_amdgcn_mfma_f32_16x16x32_f16(kf0, qf[qb][0], z, 0, 0, 0);
      sv[qb] = __builtin_amdgcn_mfma_f32_16x16x32_f16(kf1, qf[qb][1], z, 0, 0, 0);
    }
    __builtin_amdgcn_s_setprio(0);
    // prefetch next iter (last prefetch overreads into adjacent ws buffers - safe)
    f16x8 nk0 = *(const f16x8*)(kptrn);
    f16x8 nk1 = *(const f16x8*)(kptrn + 32);
    f16x4 nv[4];
#pragma unroll
    for (int cb = 0; cb < 4; cb++) nv[cb] = *(const f16x4*)(vptrn + cb * 256);
    f16x4 pk[4];
#pragma unroll
    for (int qb = 0; qb < 4; qb++) {
      float e0 = __builtin_amdgcn_exp2f(sv[qb][0]);
      float e1 = __builtin_amdgcn_exp2f(sv[qb][1]);
      float e2 = __builtin_amdgcn_exp2f(sv[qb][2]);
      float e3 = __builtin_amdgcn_exp2f(sv[qb][3]);
      union { h2 h[2]; f16x4 v4; } u;
      u.h[0] = __builtin_amdgcn_cvt_pkrtz(e0, e1);
      u.h[1] = __builtin_amdgcn_cvt_pkrtz(e2, e3);
      pk[qb] = u.v4;
    }
    __builtin_amdgcn_s_setprio(1);
#pragma unroll
    for (int qb = 0; qb < 4; qb++) {
#pragma unroll
      for (int cb = 0; cb < 4; cb++)
        oacc[qb][cb] = __builtin_amdgcn_mfma_f32_16x16x16f16(vf[cb], pk[qb], oacc[qb][cb], 0, 0, 0);
      lfrag[qb] = __builtin_amdgcn_mfma_f32_16x16x16f16(ones, pk[qb], lfrag[qb], 0, 0, 0);
    }
    __builtin_amdgcn_s_setprio(0);
    kf0 = nk0; kf1 = nk1;
#pragma unroll
    for (int cb = 0; cb < 4; cb++) vf[cb] = nv[cb];
    kptr = kptrn; vptr = vptrn;
  }
  if (lane < 16) {
#pragma unroll
    for (int qb = 0; qb < 4; qb++) lsum[wv][qb * 16 + lane] = lfrag[qb][0];
  }
  for (int w = 0; w < 4; w++) {
    __syncthreads();
    if (wv == w) {
#pragma unroll
      for (int qb = 0; qb < 4; qb++)
#pragma unroll
        for (int cb = 0; cb < 4; cb++) {
          float* a = &ol[qb * 16 + ll][cb * 16 + 4 * lg];
          if (w == 0) {
            *(f32x4*)a = oacc[qb][cb];
          } else {
            f32x4 t = *(f32x4*)a;
            t += oacc[qb][cb];
            *(f32x4*)a = t;
          }
        }
    }
  }
  __syncthreads();
  {
    int n = tid >> 2, cq = (tid & 3) * 16;
    float lt = lsum[0][n] + lsum[1][n] + lsum[2][n] + lsum[3][n];
    float inv = 1.f / lt;
    union { _Float16 hh[16]; uint4 u[2]; } pk2;
#pragma unroll
    for (int j = 0; j < 16; j++) pk2.hh[j] = (_Float16)(ol[n][cq + j] * inv);
    uint4* dst = (uint4*)(po + ((size_t)(s * 4 + b) * N + n0 + n) * 64 + cq);
    dst[0] = pk2.u[0]; dst[1] = pk2.u[1];
    if (tid < 64)
      pl[(size_t)(s * 4 + b) * N + n0 + tid] =
          lsum[0][tid] + lsum[1][tid] + lsum[2][tid] + lsum[3][tid];
  }
}

// ---------- out = out_w @ (4-split combine of po) + out_b + x2   (writes d_out)
__global__ void __launch_bounds__(256) k_outproj(const _Float16* __restrict__ po,
                                                 const float* __restrict__ pl,
                                                 const float* __restrict__ w,
                                                 const float* __restrict__ bias,
                                                 const float* __restrict__ x2,
                                                 float* __restrict__ out) {
  int b = blockIdx.x >> 6, nt = blockIdx.x & 63;
  int n0 = nt * 64;
  __shared__ __align__(16) float wl2[64][68];
  __shared__ __align__(16) float ol[64][68];
  __shared__ float wsc[4][64];
  int tid = threadIdx.x;
  if (tid < 64) {
    float l0 = pl[((size_t)(0 * 4 + b)) * N + n0 + tid];
    float l1 = pl[((size_t)(1 * 4 + b)) * N + n0 + tid];
    float l2 = pl[((size_t)(2 * 4 + b)) * N + n0 + tid];
    float l3 = pl[((size_t)(3 * 4 + b)) * N + n0 + tid];
    float inv = 1.f / (l0 + l1 + l2 + l3);
    wsc[0][tid] = l0 * inv; wsc[1][tid] = l1 * inv;
    wsc[2][tid] = l2 * inv; wsc[3][tid] = l3 * inv;
  }
  for (int i = tid; i < 4096; i += 256) wl2[i >> 6][i & 63] = w[i];
  __syncthreads();
  for (int base = tid; base < 1024; base += 256) {
    int n = base >> 4, c0 = (base & 15) * 4;
    float a0 = 0.f, a1 = 0.f, a2 = 0.f, a3 = 0.f;
#pragma unroll
    for (int s = 0; s < 4; s++) {
      f16x4 pv = *(const f16x4*)&po[((size_t)(s * 4 + b) * N + n0 + n) * 64 + c0];
      float wsv = wsc[s][n];
      a0 += (float)pv[0] * wsv; a1 += (float)pv[1] * wsv;
      a2 += (float)pv[2] * wsv; a3 += (float)pv[3] * wsv;
    }
    ol[n][c0] = a0; ol[n][c0 + 1] = a1; ol[n][c0 + 2] = a2; ol[n][c0 + 3] = a3;
  }
  __syncthreads();
  int co = tid & 63, ng = tid >> 6;
  float acc16[16];
#pragma unroll
  for (int i = 0; i < 16; i++) acc16[i] = 0.f;
  for (int c4 = 0; c4 < 16; c4++) {
    float4 wv = *(const float4*)&wl2[co][c4 * 4];
#pragma unroll
    for (int i = 0; i < 16; i++) {
      float4 ov = *(const float4*)&ol[ng * 16 + i][c4 * 4];
      acc16[i] += wv.x * ov.x + wv.y * ov.y + wv.z * ov.z + wv.w * ov.w;
    }
  }
  float bv = bias[co];
  __syncthreads();
#pragma unroll
  for (int i = 0; i < 16; i++) ol[ng * 16 + i][co] = acc16[i] + bv;
  __syncthreads();
  for (int kk = 0; kk < 16; kk++) {
    int i = tid + kk * 256;
    int c2 = i >> 6, nl = i & 63;
    size_t idx = ((size_t)(b * C + c2)) * N + n0 + nl;
    out[idx] = ol[nl][c2] + x2[idx];
  }
}

extern "C" void kernel_launch(void* const* d_in, const int* in_sizes, int n_in,
                              void* d_out, int out_size, void* d_ws, size_t ws_size,
                              hipStream_t stream) {
  (void)in_sizes; (void)n_in; (void)out_size; (void)ws_size;
  const float* x       = (const float*)d_in[0];
  const float* temb    = (const float*)d_in[1];
  const float* gn1_g   = (const float*)d_in[2];
  const float* gn1_b   = (const float*)d_in[3];
  const float* conv1_w = (const float*)d_in[4];
  const float* conv1_b = (const float*)d_in[5];
  const float* mlp_w   = (const float*)d_in[6];
  const float* mlp_b   = (const float*)d_in[7];
  const float* gn2_g   = (const float*)d_in[8];
  const float* gn2_b   = (const float*)d_in[9];
  const float* conv2_w = (const float*)d_in[10];
  const float* conv2_b = (const float*)d_in[11];
  const float* agn_g   = (const float*)d_in[12];
  const float* agn_b   = (const float*)d_in[13];
  const float* qkv_w   = (const float*)d_in[14];
  const float* out_w   = (const float*)d_in[15];
  const float* out_b   = (const float*)d_in[16];
  float* out = (float*)d_out;
  float* ws = (float*)d_ws;
  const size_t F = 1048576;
  float* h        = ws;                         // conv1 out (fp32)
  float* x2       = ws + F;                     // conv2 out + residual (fp32)
  _Float16* qh    = (_Float16*)(ws + 2 * F);    // f16 [b][n][c]
  _Float16* khb   = qh + F;                     // f16 [b][n][c]
  _Float16* vhb   = khb + F;                    // f16 tile-major [b][n/16][c][n%16]
  float2* pst1 = (float2*)(vhb + F);            // 256 float2 (x stats)
  float2* pst2 = pst1 + 256;                    // 256 float2 (h stats)
  float2* pst3 = pst2 + 256;                    // 256 float2 (x2 stats)
  float* tb    = (float*)(pst3 + 256);          // 256
  _Float16* wf1 = (_Float16*)(tb + 256);        // 110592 f16
  _Float16* wf2 = wf1 + 27 * 64 * 64;
  _Float16* po  = wf2 + 27 * 64 * 64;           // 4M f16
  float* pl     = (float*)(po + 4 * F);         // 65536 floats

  k_prepgn<<<314, 256, 0, stream>>>(conv1_w, conv2_w, temb, mlp_w, mlp_b, x,
                                    wf1, wf2, tb, pst1);
  k_conv3f<<<256, 256, 0, stream>>>(x, pst1, gn1_g, gn1_b, wf1, conv1_b, tb, nullptr, h);
  k_gnpart<<<256, 256, 0, stream>>>(h, pst2);
  k_conv3f<<<256, 256, 0, stream>>>(h, pst2, gn2_g, gn2_b, wf2, conv2_b, nullptr, x, x2);
  k_gnpart<<<256, 256, 0, stream>>>(x2, pst3);
  k_qkv<<<256, 256, 0, stream>>>(x2, pst3, agn_g, agn_b, qkv_w, qh, khb, vhb);
  k_attn<<<1024, 256, 0, stream>>>(qh, khb, vhb, po, pl);
  k_outproj<<<256, 256, 0, stream>>>(po, pl, out_w, out_b, x2, out);
}